// Round 6
// baseline (3429.826 us; speedup 1.0000x reference)
//
#include <hip/hip_runtime.h>
#include <math.h>

// Round 6: round-5 defensive structure, dtype corrected to FLOAT32 per the
// reference (x, base_W, base_b, A, B, gate_v, alphas are f32; top_k int32;
// output f32). No MFMA, no vector casts — correctness first; optimize after green.

#define DEV __device__ __forceinline__

// clamped f32 load: any out-of-range index reads element 0 instead of faulting
DEV float ldf(const float* __restrict__ p, long long i, long long n) {
  if (i < 0 || i >= n) i = 0;
  return p[i];
}

struct Route { int e0, e1; float c0, c1; };

#define MAX_T 8192
#define MAX_ER 256
__device__ Route g_route[MAX_T];
__device__ float g_mid[MAX_T * MAX_ER];  // 8 MB; fully rewritten before any read, every call

// ---------------- Router: cosine scores -> top-2 -> softmax -> * alpha/r ----------------
__global__ __launch_bounds__(256) void router_kernel(
    const float* __restrict__ x, long long nX,
    const float* __restrict__ gate_v, long long nG,
    const float* __restrict__ alphas, long long nAl,
    const int* __restrict__ topk_ptr, int has_topk,
    int T, int d, int r, int E) {
  const int wave = threadIdx.x >> 6, lane = threadIdx.x & 63;
  const int t = blockIdx.x * 4 + wave;
  if (t >= T || t >= MAX_T) return;
  float xx = 0.f, dot[16], vv[16];
#pragma unroll
  for (int e = 0; e < 16; ++e) { dot[e] = 0.f; vv[e] = 0.f; }
  for (int i = lane; i < d; i += 64) {
    const float xv = ldf(x, (long long)t * d + i, nX);
    xx += xv * xv;
#pragma unroll
    for (int e = 0; e < 16; ++e) {
      if (e < E) {
        const float gvv = ldf(gate_v, (long long)e * d + i, nG);
        dot[e] += xv * gvv;
        vv[e] += gvv * gvv;
      }
    }
  }
#pragma unroll
  for (int m = 1; m < 64; m <<= 1) {
    xx += __shfl_xor(xx, m);
#pragma unroll
    for (int e = 0; e < 16; ++e) {
      dot[e] += __shfl_xor(dot[e], m);
      vv[e] += __shfl_xor(vv[e], m);
    }
  }
  const float inv_sd = 1.0f / sqrtf((float)d);
  const float xnorm = sqrtf(xx) + 1e-6f;
  float s[16];
#pragma unroll
  for (int e = 0; e < 16; ++e)
    s[e] = (e < E) ? dot[e] / (xnorm * (sqrtf(vv[e]) + 1e-6f)) * inv_sd : -1e30f;
  int e0 = 0; float s0 = s[0];
#pragma unroll
  for (int e = 1; e < 16; ++e) if (s[e] > s0) { s0 = s[e]; e0 = e; }
  int e1 = (e0 == 0) ? 1 : 0; float s1 = s[e1];
#pragma unroll
  for (int e = 0; e < 16; ++e) if (e != e0 && s[e] > s1) { s1 = s[e]; e1 = e; }
  const int k = has_topk ? *topk_ptr : 2;
  float w0 = 1.f, w1 = 0.f;
  if (k >= 2) {
    const float ex = expf(s1 - s0);  // s0 >= s1 so ex <= 1: stable
    w0 = 1.f / (1.f + ex);
    w1 = ex / (1.f + ex);
  } else {
    e1 = e0;
  }
  if (lane == 0) {
    Route rt;
    rt.e0 = e0; rt.e1 = e1;
    rt.c0 = w0 * ldf(alphas, e0, nAl) / (float)r;
    rt.c1 = w1 * ldf(alphas, e1, nAl) / (float)r;
    g_route[t] = rt;
  }
}

// ---------------- Tiled vector GEMM: C[T x (d_out+Er)] = x @ [W^T | A_flat^T] ----------------
#define TM 64
#define TN 64
#define TK 32

__global__ __launch_bounds__(256) void gemm_vec(
    const float* __restrict__ X, long long nX,
    const float* __restrict__ W, long long nW,
    const float* __restrict__ Afl, long long nA,
    const float* __restrict__ bias, long long nBias,
    float* __restrict__ Out, long long nOut,
    int K, int d_out, int Er, int T) {
  __shared__ float Xs[TM][TK + 1];
  __shared__ float Ws[TN][TK + 1];
  const int tid = threadIdx.x;
  const int Mb = blockIdx.y * TM;
  const int Nb = blockIdx.x * TN;
  const bool isMid = (Nb >= d_out);
  const int ty = tid >> 4, tx = tid & 15;
  const int lrow = tid >> 2;          // 0..63
  const int lc0 = (tid & 3) * 8;      // 0,8,16,24

  float acc[4][4];
#pragma unroll
  for (int i = 0; i < 4; ++i)
#pragma unroll
    for (int j = 0; j < 4; ++j) acc[i][j] = 0.f;

  for (int k0 = 0; k0 < K; k0 += TK) {
#pragma unroll
    for (int j = 0; j < 8; ++j) {
      const int col = lc0 + j;
      Xs[lrow][col] = ldf(X, (long long)(Mb + lrow) * K + k0 + col, nX);
      const int wr = Nb + lrow;
      Ws[lrow][col] = isMid ? ldf(Afl, (long long)(wr - d_out) * K + k0 + col, nA)
                            : ldf(W, (long long)wr * K + k0 + col, nW);
    }
    __syncthreads();
#pragma unroll 8
    for (int kk = 0; kk < TK; ++kk) {
      const float a0 = Xs[ty * 4 + 0][kk], a1 = Xs[ty * 4 + 1][kk];
      const float a2 = Xs[ty * 4 + 2][kk], a3 = Xs[ty * 4 + 3][kk];
      const float b0 = Ws[tx * 4 + 0][kk], b1 = Ws[tx * 4 + 1][kk];
      const float b2 = Ws[tx * 4 + 2][kk], b3 = Ws[tx * 4 + 3][kk];
      acc[0][0] += a0 * b0; acc[0][1] += a0 * b1; acc[0][2] += a0 * b2; acc[0][3] += a0 * b3;
      acc[1][0] += a1 * b0; acc[1][1] += a1 * b1; acc[1][2] += a1 * b2; acc[1][3] += a1 * b3;
      acc[2][0] += a2 * b0; acc[2][1] += a2 * b1; acc[2][2] += a2 * b2; acc[2][3] += a2 * b3;
      acc[3][0] += a3 * b0; acc[3][1] += a3 * b1; acc[3][2] += a3 * b2; acc[3][3] += a3 * b3;
    }
    __syncthreads();
  }

#pragma unroll
  for (int i = 0; i < 4; ++i) {
    const int row = Mb + ty * 4 + i;
#pragma unroll
    for (int j = 0; j < 4; ++j) {
      const int col = Nb + tx * 4 + j;
      if (!isMid) {
        const long long idx = (long long)row * d_out + col;
        if (row < T && idx >= 0 && idx < nOut)
          Out[idx] = acc[i][j] + ldf(bias, col, nBias);
      } else {
        const int mc = col - d_out;
        if (row < T && row < MAX_T && mc >= 0 && mc < Er && mc < MAX_ER) {
          const long long mi = (long long)row * Er + mc;
          if (mi >= 0 && mi < (long long)MAX_T * MAX_ER) g_mid[mi] = acc[i][j];
        }
      }
    }
  }
}

// ---------------- Combine: out[t][o] += sum over 2 experts of w_e * (B[e][o][:] . mid[t,e,:]) ----------------
__global__ __launch_bounds__(256) void combine_kernel(
    const float* __restrict__ Bw, long long nB,
    float* __restrict__ Out, long long nOut,
    int T, int d_out, int r, int Er, int E) {
  const int t = blockIdx.x;
  if (t >= T || t >= MAX_T) return;
  const int tid = threadIdx.x;
  __shared__ float sm0[64], sm1[64];
  __shared__ Route srt;
  if (tid == 0) {
    Route rt = g_route[t];
    rt.e0 = min(max(rt.e0, 0), E - 1);
    rt.e1 = min(max(rt.e1, 0), E - 1);
    srt = rt;
  }
  __syncthreads();
  const Route rt = srt;
  if (tid < 64) sm0[tid] = 0.f;
  else if (tid < 128) sm1[tid - 64] = 0.f;
  // same thread writes the same slot below — no race, no extra barrier needed
  if (tid < r && tid < 64) {
    const long long mi = (long long)t * Er + (long long)rt.e0 * r + tid;
    sm0[tid] = rt.c0 * ((mi >= 0 && mi < (long long)MAX_T * MAX_ER) ? g_mid[mi] : 0.f);
  }
  if (tid >= 64 && tid < 128 && (tid - 64) < r) {
    const int i = tid - 64;
    const long long mi = (long long)t * Er + (long long)rt.e1 * r + i;
    sm1[i] = rt.c1 * ((mi >= 0 && mi < (long long)MAX_T * MAX_ER) ? g_mid[mi] : 0.f);
  }
  __syncthreads();
  const int rl = min(r, 64);
  for (int o = tid; o < d_out; o += 256) {
    float acc = 0.f;
    for (int i = 0; i < rl; ++i) {
      acc += ldf(Bw, (long long)rt.e0 * d_out * r + (long long)o * r + i, nB) * sm0[i];
      acc += ldf(Bw, (long long)rt.e1 * d_out * r + (long long)o * r + i, nB) * sm1[i];
    }
    const long long idx = (long long)t * d_out + o;
    if (idx >= 0 && idx < nOut) Out[idx] = Out[idx] + acc;
  }
}

extern "C" void kernel_launch(void* const* d_in, const int* in_sizes, int n_in,
                              void* d_out, int out_size, void* d_ws, size_t ws_size,
                              hipStream_t stream) {
  if (n_in < 7 || !d_out) return;
  const float* x    = (const float*)d_in[0];
  const float* W    = (const float*)d_in[1];
  const float* bias = (const float*)d_in[2];
  const float* A    = (const float*)d_in[3];
  const float* B    = (const float*)d_in[4];
  const float* gv   = (const float*)d_in[5];
  const float* al   = (const float*)d_in[6];
  const int has_topk = (n_in > 7 && in_sizes[7] >= 1) ? 1 : 0;
  const int* topk = has_topk ? (const int*)d_in[7] : nullptr;
  float* out = (float*)d_out;

  const long long nX = in_sizes[0], nW = in_sizes[1], nBias = in_sizes[2];
  const long long nA = in_sizes[3], nB = in_sizes[4], nG = in_sizes[5], nAl = in_sizes[6];
  const long long nOut = (long long)out_size;

  const int E = in_sizes[6] > 0 ? in_sizes[6] : 1;               // 16
  int d = (int)(nG / E); if (d < 1) d = 1;                       // 2048
  const int d_out_dim = in_sizes[2] > 0 ? in_sizes[2] : 1;       // 2048
  int T = (int)(nX / d);                                         // 8192
  int r = (int)(nA / ((long long)E * d)); if (r < 1) r = 1;      // 16
  const int Er = E * r;                                          // 256
  if (T < 1) return;
  if (T > MAX_T) T = MAX_T;

  router_kernel<<<(T + 3) / 4, 256, 0, stream>>>(x, nX, gv, nG, al, nAl, topk, has_topk, T, d, r, E);
  dim3 grid((d_out_dim + Er + TN - 1) / TN, (T + TM - 1) / TM);
  gemm_vec<<<grid, 256, 0, stream>>>(x, nX, W, nW, A, nA, bias, nBias, out, nOut, d, d_out_dim, Er, T);
  combine_kernel<<<T, 256, 0, stream>>>(B, nB, out, nOut, T, d_out_dim, r, Er, E);
}

// Round 7
// 604.420 us; speedup vs baseline: 5.6746x; 5.6746x over previous
//
#include <hip/hip_runtime.h>
#include <math.h>

// Round 7: f32 interface confirmed (round 6 passed). Now move the GEMM to
// bf16 MFMA: cvt pre-pass (f32 -> bf16 statics), m93-style 128x128 MFMA GEMM
// with plain ds-write staging, vectorized router/combine. All global accesses
// remain bounds-clamped (defensive discipline from round 5).

typedef unsigned short u16;
typedef __attribute__((ext_vector_type(8))) short short8;
typedef __attribute__((ext_vector_type(4))) float floatx4;

#define DEV __device__ __forceinline__

DEV u16 f2b(float f) { unsigned int u; __builtin_memcpy(&u, &f, 4); u += 0x7fffu + ((u >> 16) & 1u); return (u16)(u >> 16); }
DEV float ldf(const float* __restrict__ p, long long i, long long n) { if (i < 0 || i >= n) i = 0; return p[i]; }
DEV float4 ldf4(const float* __restrict__ p, long long i, long long n) {
  if (i < 0 || i + 4 > n) { float4 z; z.x = z.y = z.z = z.w = 0.f; return z; }
  return *(const float4*)(p + i);
}

struct Route { int e0, e1; float c0, c1; };

#define MAX_T 8192
#define MAX_K 2048
#define MAX_DOUT 2048
#define MAX_ER 256

// Static device scratch (referenced directly by kernels; no host symbol lookup).
// All fully rewritten before any read on every call.
__device__ Route g_route[MAX_T];
__device__ float g_mid[(size_t)MAX_T * MAX_ER];
__device__ __align__(16) u16 g_xb[(size_t)MAX_T * MAX_K];     // x as bf16
__device__ __align__(16) u16 g_wb[(size_t)MAX_DOUT * MAX_K];  // base_W as bf16
__device__ __align__(16) u16 g_ab[(size_t)MAX_ER * MAX_K];    // A as bf16

// ---------------- Convert f32 -> bf16 (RNE) into the selected static buffer ----------------
__global__ __launch_bounds__(256) void cvt_bf16(const float* __restrict__ src, long long n, int which) {
  u16* dst; long long cap;
  if (which == 0) { dst = g_xb; cap = (long long)MAX_T * MAX_K; }
  else if (which == 1) { dst = g_wb; cap = (long long)MAX_DOUT * MAX_K; }
  else { dst = g_ab; cap = (long long)MAX_ER * MAX_K; }
  const long long stride = (long long)gridDim.x * 256 * 4;
  for (long long i4 = ((long long)blockIdx.x * 256 + threadIdx.x) * 4; i4 < n; i4 += stride) {
    if (i4 + 4 <= n && i4 + 4 <= cap) {
      const float4 v = *(const float4*)(src + i4);
      ushort4 o;
      o.x = f2b(v.x); o.y = f2b(v.y); o.z = f2b(v.z); o.w = f2b(v.w);
      *(ushort4*)(dst + i4) = o;
    } else {
      for (long long j = i4; j < n && j < cap; ++j) dst[j] = f2b(src[j]);
    }
  }
}

// ---------------- Router: cosine scores -> top-2 -> softmax -> * alpha/r (exact f32) ----------------
__global__ __launch_bounds__(256) void router_kernel(
    const float* __restrict__ x, long long nX,
    const float* __restrict__ gate_v, long long nG,
    const float* __restrict__ alphas, long long nAl,
    const int* __restrict__ topk_ptr, int has_topk,
    int T, int d, int r, int E) {
  const int wave = threadIdx.x >> 6, lane = threadIdx.x & 63;
  const int t = blockIdx.x * 4 + wave;
  if (t >= T || t >= MAX_T) return;
  float xx = 0.f, dot[16], vv[16];
#pragma unroll
  for (int e = 0; e < 16; ++e) { dot[e] = 0.f; vv[e] = 0.f; }
  const int dvec = ((d & 3) == 0) ? (d / 256) * 256 : 0;  // region covered by float4 loop
  for (int i = lane * 4; i < dvec; i += 256) {
    const float4 xv = ldf4(x, (long long)t * d + i, nX);
    xx += xv.x * xv.x + xv.y * xv.y + xv.z * xv.z + xv.w * xv.w;
#pragma unroll
    for (int e = 0; e < 16; ++e) {
      if (e < E) {
        const float4 g = ldf4(gate_v, (long long)e * d + i, nG);
        dot[e] += xv.x * g.x + xv.y * g.y + xv.z * g.z + xv.w * g.w;
        vv[e] += g.x * g.x + g.y * g.y + g.z * g.z + g.w * g.w;
      }
    }
  }
  for (int i = dvec + lane; i < d; i += 64) {
    const float xv = ldf(x, (long long)t * d + i, nX);
    xx += xv * xv;
#pragma unroll
    for (int e = 0; e < 16; ++e) {
      if (e < E) {
        const float g = ldf(gate_v, (long long)e * d + i, nG);
        dot[e] += xv * g;
        vv[e] += g * g;
      }
    }
  }
#pragma unroll
  for (int m = 1; m < 64; m <<= 1) {
    xx += __shfl_xor(xx, m);
#pragma unroll
    for (int e = 0; e < 16; ++e) {
      dot[e] += __shfl_xor(dot[e], m);
      vv[e] += __shfl_xor(vv[e], m);
    }
  }
  const float inv_sd = 1.0f / sqrtf((float)d);
  const float xnorm = sqrtf(xx) + 1e-6f;
  float s[16];
#pragma unroll
  for (int e = 0; e < 16; ++e)
    s[e] = (e < E) ? dot[e] / (xnorm * (sqrtf(vv[e]) + 1e-6f)) * inv_sd : -1e30f;
  int e0 = 0; float s0 = s[0];
#pragma unroll
  for (int e = 1; e < 16; ++e) if (s[e] > s0) { s0 = s[e]; e0 = e; }
  int e1 = (e0 == 0) ? 1 : 0; float s1 = s[e1];
#pragma unroll
  for (int e = 0; e < 16; ++e) if (e != e0 && s[e] > s1) { s1 = s[e]; e1 = e; }
  const int k = has_topk ? *topk_ptr : 2;
  float w0 = 1.f, w1 = 0.f;
  if (k >= 2) {
    const float ex = expf(s1 - s0);  // s0 >= s1 so ex <= 1: stable
    w0 = 1.f / (1.f + ex);
    w1 = ex / (1.f + ex);
  } else {
    e1 = e0;
  }
  if (lane == 0) {
    Route rt;
    rt.e0 = e0; rt.e1 = e1;
    rt.c0 = w0 * ldf(alphas, e0, nAl) / (float)r;
    rt.c1 = w1 * ldf(alphas, e1, nAl) / (float)r;
    g_route[t] = rt;
  }
}

// ---------------- MFMA GEMM: C[T x (d_out+Er)] = x @ [W^T | A_flat^T], bf16 in / f32 out ----------------
#define BM 128
#define BN 128
#define BK 32

__global__ __launch_bounds__(256) void gemm_mfma(
    const float* __restrict__ bias, long long nBias,
    float* __restrict__ Out, long long nOut,
    int K, int d_out, int Er, int T) {
  __shared__ __align__(16) u16 As[BM * BK];
  __shared__ __align__(16) u16 Bs[BN * BK];
  const int tid = threadIdx.x;
  const int lane = tid & 63;
  const int w = tid >> 6;
  const int Mb = blockIdx.y * BM;
  const int Nb = blockIdx.x * BN;
  const int wm = w >> 1, wn = w & 1;
  const int lrow = tid >> 2;          // 0..63
  const int lcol = (tid & 3) * 8;     // 0,8,16,24
  const long long nXb = (long long)T * K;
  const long long nWb = (long long)d_out * K;
  const long long nAb = (long long)Er * K;

  floatx4 acc[4][4];
#pragma unroll
  for (int mt = 0; mt < 4; ++mt)
#pragma unroll
    for (int nt = 0; nt < 4; ++nt) acc[mt][nt] = (floatx4){0.f, 0.f, 0.f, 0.f};

  for (int k0 = 0; k0 < K; k0 += BK) {
#pragma unroll
    for (int it = 0; it < 2; ++it) {
      const int row = lrow + it * 64;
      long long gi = (long long)(Mb + row) * K + k0 + lcol;
      if (gi < 0 || gi + 8 > nXb) gi = 0;  // clamp (shapes exact -> never taken)
      *(short8*)&As[row * BK + lcol] = *(const short8*)&g_xb[gi];
    }
#pragma unroll
    for (int it = 0; it < 2; ++it) {
      const int row = lrow + it * 64;
      const int col = Nb + row;
      const u16* src; long long gi, lim;
      if (col >= d_out) { src = g_ab; gi = (long long)(col - d_out) * K + k0 + lcol; lim = nAb; }
      else             { src = g_wb; gi = (long long)col * K + k0 + lcol; lim = nWb; }
      if (gi < 0 || gi + 8 > lim) gi = 0;
      *(short8*)&Bs[row * BK + lcol] = *(const short8*)&src[gi];
    }
    __syncthreads();
    short8 a[4], b[4];
#pragma unroll
    for (int mt = 0; mt < 4; ++mt)
      a[mt] = *(const short8*)&As[(wm * 64 + mt * 16 + (lane & 15)) * BK + (lane >> 4) * 8];
#pragma unroll
    for (int nt = 0; nt < 4; ++nt)
      b[nt] = *(const short8*)&Bs[(wn * 64 + nt * 16 + (lane & 15)) * BK + (lane >> 4) * 8];
#pragma unroll
    for (int mt = 0; mt < 4; ++mt)
#pragma unroll
      for (int nt = 0; nt < 4; ++nt)
        acc[mt][nt] = __builtin_amdgcn_mfma_f32_16x16x32_bf16(a[mt], b[nt], acc[mt][nt], 0, 0, 0);
    __syncthreads();
  }

  // epilogue: C/D map col=lane&15, row=(lane>>4)*4+reg  [m89/m91-verified]
  const int colb = Nb + wn * 64 + (lane & 15);
  const int rowb = Mb + wm * 64 + (lane >> 4) * 4;
#pragma unroll
  for (int nt = 0; nt < 4; ++nt) {
    const int col = colb + nt * 16;
#pragma unroll
    for (int mt = 0; mt < 4; ++mt) {
      const int row = rowb + mt * 16;
#pragma unroll
      for (int i = 0; i < 4; ++i) {
        const int rr = row + i;
        if (rr >= T) continue;
        if (col < d_out) {
          const long long idx = (long long)rr * d_out + col;
          if (idx >= 0 && idx < nOut) Out[idx] = acc[mt][nt][i] + ldf(bias, col, nBias);
        } else {
          const int mc = col - d_out;
          if (mc < Er && rr < MAX_T && mc < MAX_ER)
            g_mid[(long long)rr * Er + mc] = acc[mt][nt][i];
        }
      }
    }
  }
}

// ---------------- Combine: out[t][o] += w_e0*(B[e0][o].mid_e0) + w_e1*(B[e1][o].mid_e1) ----------------
__global__ __launch_bounds__(256) void combine_kernel(
    const float* __restrict__ Bw, long long nB,
    float* __restrict__ Out, long long nOut,
    int T, int d_out, int r, int Er, int E) {
  const int t = blockIdx.x;
  if (t >= T || t >= MAX_T) return;
  const int tid = threadIdx.x;
  __shared__ float sm0[64], sm1[64];
  __shared__ Route srt;
  if (tid == 0) {
    Route rt = g_route[t];
    rt.e0 = min(max(rt.e0, 0), E - 1);
    rt.e1 = min(max(rt.e1, 0), E - 1);
    srt = rt;
  }
  __syncthreads();
  const Route rt = srt;
  if (tid < 64) sm0[tid] = 0.f;
  else if (tid < 128) sm1[tid - 64] = 0.f;
  if (tid < r && tid < 64) {
    const long long mi = (long long)t * Er + (long long)rt.e0 * r + tid;
    sm0[tid] = rt.c0 * ((mi >= 0 && mi < (long long)MAX_T * MAX_ER) ? g_mid[mi] : 0.f);
  }
  if (tid >= 64 && tid < 128 && (tid - 64) < r) {
    const int i = tid - 64;
    const long long mi = (long long)t * Er + (long long)rt.e1 * r + i;
    sm1[i] = rt.c1 * ((mi >= 0 && mi < (long long)MAX_T * MAX_ER) ? g_mid[mi] : 0.f);
  }
  __syncthreads();
  if (r == 16) {
    float4 m0[4], m1[4];
#pragma unroll
    for (int j = 0; j < 4; ++j) {
      m0[j].x = sm0[j*4+0]; m0[j].y = sm0[j*4+1]; m0[j].z = sm0[j*4+2]; m0[j].w = sm0[j*4+3];
      m1[j].x = sm1[j*4+0]; m1[j].y = sm1[j*4+1]; m1[j].z = sm1[j*4+2]; m1[j].w = sm1[j*4+3];
    }
    const long long b0 = (long long)rt.e0 * d_out * 16;
    const long long b1 = (long long)rt.e1 * d_out * 16;
    for (int o = tid; o < d_out; o += 256) {
      float acc = 0.f;
#pragma unroll
      for (int j = 0; j < 4; ++j) {
        const float4 q = ldf4(Bw, b0 + (long long)o * 16 + j * 4, nB);
        acc += q.x * m0[j].x + q.y * m0[j].y + q.z * m0[j].z + q.w * m0[j].w;
      }
#pragma unroll
      for (int j = 0; j < 4; ++j) {
        const float4 q = ldf4(Bw, b1 + (long long)o * 16 + j * 4, nB);
        acc += q.x * m1[j].x + q.y * m1[j].y + q.z * m1[j].z + q.w * m1[j].w;
      }
      const long long idx = (long long)t * d_out + o;
      if (idx >= 0 && idx < nOut) Out[idx] = Out[idx] + acc;
    }
  } else {
    const int rl = min(r, 64);
    for (int o = tid; o < d_out; o += 256) {
      float acc = 0.f;
      for (int i = 0; i < rl; ++i) {
        acc += ldf(Bw, (long long)rt.e0 * d_out * r + (long long)o * r + i, nB) * sm0[i];
        acc += ldf(Bw, (long long)rt.e1 * d_out * r + (long long)o * r + i, nB) * sm1[i];
      }
      const long long idx = (long long)t * d_out + o;
      if (idx >= 0 && idx < nOut) Out[idx] = Out[idx] + acc;
    }
  }
}

extern "C" void kernel_launch(void* const* d_in, const int* in_sizes, int n_in,
                              void* d_out, int out_size, void* d_ws, size_t ws_size,
                              hipStream_t stream) {
  if (n_in < 7 || !d_out) return;
  const float* x    = (const float*)d_in[0];
  const float* W    = (const float*)d_in[1];
  const float* bias = (const float*)d_in[2];
  const float* A    = (const float*)d_in[3];
  const float* B    = (const float*)d_in[4];
  const float* gv   = (const float*)d_in[5];
  const float* al   = (const float*)d_in[6];
  const int has_topk = (n_in > 7 && in_sizes[7] >= 1) ? 1 : 0;
  const int* topk = has_topk ? (const int*)d_in[7] : nullptr;
  float* out = (float*)d_out;

  const long long nX = in_sizes[0], nW = in_sizes[1], nBias = in_sizes[2];
  const long long nA = in_sizes[3], nB = in_sizes[4], nG = in_sizes[5], nAl = in_sizes[6];
  const long long nOut = (long long)out_size;

  const int E = in_sizes[6] > 0 ? in_sizes[6] : 1;               // 16
  int d = (int)(nG / E); if (d < 1) d = 1;                       // 2048
  const int d_out_dim = in_sizes[2] > 0 ? in_sizes[2] : 1;       // 2048
  int T = (int)(nX / d);                                         // 8192
  int r = (int)(nA / ((long long)E * d)); if (r < 1) r = 1;      // 16
  const int Er = E * r;                                          // 256
  if (T < 1) return;
  if (T > MAX_T) T = MAX_T;

  // convert inputs to bf16 statics
  cvt_bf16<<<8192, 256, 0, stream>>>(x, nX, 0);
  cvt_bf16<<<4096, 256, 0, stream>>>(W, nW, 1);
  cvt_bf16<<<512, 256, 0, stream>>>(A, nA, 2);

  router_kernel<<<(T + 3) / 4, 256, 0, stream>>>(x, nX, gv, nG, al, nAl, topk, has_topk, T, d, r, E);

  dim3 grid((d_out_dim + Er + BN - 1) / BN, (T + BM - 1) / BM);
  gemm_mfma<<<grid, 256, 0, stream>>>(bias, nBias, out, nOut, d, d_out_dim, Er, T);

  combine_kernel<<<T, 256, 0, stream>>>(B, nB, out, nOut, T, d_out_dim, r, Er, E);
}

// Round 8
// 481.534 us; speedup vs baseline: 7.1227x; 1.2552x over previous
//
#include <hip/hip_runtime.h>
#include <math.h>

// Round 8: r1-r4 aborts root-caused (e1=-1 on NaN scores — dtype bug, not MFMA
// or global_load_lds). Re-adopt m97 async staging for the big GEMM, turn the
// combine into a K=256 MFMA GEMM (M' @ W2^T), fuse x->bf16 into the router.

typedef unsigned short u16;
typedef __attribute__((ext_vector_type(8))) short short8;
typedef __attribute__((ext_vector_type(4))) float floatx4;

#define DEV __device__ __forceinline__

DEV u16 f2b(float f) { unsigned int u; __builtin_memcpy(&u, &f, 4); u += 0x7fffu + ((u >> 16) & 1u); return (u16)(u >> 16); }
DEV float ldf(const float* __restrict__ p, long long i, long long n) { if (i < 0 || i >= n) i = 0; return p[i]; }

DEV void async_cp16(const void* g, void* l) {
  __builtin_amdgcn_global_load_lds(
      (const __attribute__((address_space(1))) unsigned int*)g,
      (__attribute__((address_space(3))) unsigned int*)l, 16, 0, 0);
}

struct Route { int e0, e1; float c0, c1; };

#define MAX_T 8192
#define MAX_K 2048
#define MAX_DOUT 2048
#define MAX_ER 256

// Static device scratch; every buffer fully rewritten before read, each call.
__device__ Route g_route[MAX_T];
__device__ float g_mid[(size_t)MAX_T * MAX_ER];               // x@A^T (f32)
__device__ __align__(16) u16 g_xb[(size_t)MAX_T * MAX_K];     // x bf16
__device__ __align__(16) u16 g_wb[(size_t)MAX_DOUT * MAX_K];  // base_W bf16
__device__ __align__(16) u16 g_ab[(size_t)MAX_ER * MAX_K];    // A bf16
__device__ __align__(16) u16 g_mw[(size_t)MAX_T * MAX_ER];    // weighted mid bf16
__device__ __align__(16) u16 g_w2[(size_t)MAX_DOUT * MAX_ER]; // B permuted [o][e*r+j] bf16

// ---------------- f32 -> bf16 conversions for W / A ----------------
__global__ __launch_bounds__(256) void cvt_bf16(const float* __restrict__ src, long long n, int which) {
  u16* dst; long long cap;
  if (which == 1) { dst = g_wb; cap = (long long)MAX_DOUT * MAX_K; }
  else { dst = g_ab; cap = (long long)MAX_ER * MAX_K; }
  const long long stride = (long long)gridDim.x * 256 * 4;
  for (long long i4 = ((long long)blockIdx.x * 256 + threadIdx.x) * 4; i4 < n; i4 += stride) {
    if (i4 + 4 <= n && i4 + 4 <= cap) {
      const float4 v = *(const float4*)(src + i4);
      ushort4 o;
      o.x = f2b(v.x); o.y = f2b(v.y); o.z = f2b(v.z); o.w = f2b(v.w);
      *(ushort4*)(dst + i4) = o;
    } else {
      for (long long j = i4; j < n && j < cap; ++j) dst[j] = f2b(src[j]);
    }
  }
}

// ---------------- Build W2[o][e*r+j] = B[e][o][j] as bf16 ----------------
// thread = o*E + e: writes contiguous (coalesced); reads full 64B lines.
__global__ __launch_bounds__(256) void build_w2(const float* __restrict__ Bw, long long nB,
                                                int d_out, int r, int E, int Er) {
  const int gid = blockIdx.x * 256 + threadIdx.x;
  if (gid >= d_out * E) return;
  const int o = gid / E, e = gid % E;
  const long long src = ((long long)e * d_out + o) * r;
  const long long dst = (long long)o * Er + (long long)e * r;
  if (r == 16 && src + 16 <= nB) {
    short8 lo, hi;
#pragma unroll
    for (int j = 0; j < 8; ++j) lo[j] = (short)f2b(Bw[src + j]);
#pragma unroll
    for (int j = 0; j < 8; ++j) hi[j] = (short)f2b(Bw[src + 8 + j]);
    *(short8*)&g_w2[dst] = lo;
    *(short8*)&g_w2[dst + 8] = hi;
  } else {
    for (int j = 0; j < r; ++j) g_w2[dst + j] = f2b(ldf(Bw, src + j, nB));
  }
}

// ---------------- Router (exact f32) + fused x->bf16 conversion ----------------
__global__ __launch_bounds__(256) void router_cvtx(
    const float* __restrict__ x, long long nX,
    const float* __restrict__ gate_v, long long nG,
    const float* __restrict__ alphas, long long nAl,
    const int* __restrict__ topk_ptr, int has_topk,
    int T, int d, int r, int E) {
  const int wave = threadIdx.x >> 6, lane = threadIdx.x & 63;
  const int t = blockIdx.x * 4 + wave;
  if (t >= T || t >= MAX_T) return;
  float xx = 0.f, dot[16], vv[16];
#pragma unroll
  for (int e = 0; e < 16; ++e) { dot[e] = 0.f; vv[e] = 0.f; }
  const long long xbase = (long long)t * d;
  const int dvec = ((d & 3) == 0) ? d : 0;  // d=2048 -> full vec path
  for (int i = lane * 4; i < dvec; i += 256) {
    const float4 xv = *(const float4*)(x + xbase + i);
    xx += xv.x * xv.x + xv.y * xv.y + xv.z * xv.z + xv.w * xv.w;
    ushort4 ob; ob.x = f2b(xv.x); ob.y = f2b(xv.y); ob.z = f2b(xv.z); ob.w = f2b(xv.w);
    *(ushort4*)&g_xb[xbase + i] = ob;
#pragma unroll
    for (int e = 0; e < 16; ++e) {
      if (e < E) {
        const float4 g = *(const float4*)(gate_v + (long long)e * d + i);
        dot[e] += xv.x * g.x + xv.y * g.y + xv.z * g.z + xv.w * g.w;
        vv[e] += g.x * g.x + g.y * g.y + g.z * g.z + g.w * g.w;
      }
    }
  }
  for (int i = dvec + lane; i < d; i += 64) {
    const float xv = ldf(x, xbase + i, nX);
    g_xb[xbase + i] = f2b(xv);
    xx += xv * xv;
#pragma unroll
    for (int e = 0; e < 16; ++e) {
      if (e < E) {
        const float g = ldf(gate_v, (long long)e * d + i, nG);
        dot[e] += xv * g;
        vv[e] += g * g;
      }
    }
  }
#pragma unroll
  for (int m = 1; m < 64; m <<= 1) {
    xx += __shfl_xor(xx, m);
#pragma unroll
    for (int e = 0; e < 16; ++e) {
      dot[e] += __shfl_xor(dot[e], m);
      vv[e] += __shfl_xor(vv[e], m);
    }
  }
  const float inv_sd = 1.0f / sqrtf((float)d);
  const float xnorm = sqrtf(xx) + 1e-6f;
  float s[16];
#pragma unroll
  for (int e = 0; e < 16; ++e)
    s[e] = (e < E) ? dot[e] / (xnorm * (sqrtf(vv[e]) + 1e-6f)) * inv_sd : -1e30f;
  int e0 = 0; float s0 = s[0];
#pragma unroll
  for (int e = 1; e < 16; ++e) if (s[e] > s0) { s0 = s[e]; e0 = e; }
  int e1 = (e0 == 0) ? 1 : 0; float s1 = s[e1];
#pragma unroll
  for (int e = 0; e < 16; ++e) if (e != e0 && s[e] > s1) { s1 = s[e]; e1 = e; }
  const int k = has_topk ? *topk_ptr : 2;
  float w0 = 1.f, w1 = 0.f;
  if (k >= 2) {
    const float ex = expf(s1 - s0);  // s0 >= s1 -> stable
    w0 = 1.f / (1.f + ex);
    w1 = ex / (1.f + ex);
  } else {
    e1 = e0;
  }
  if (lane == 0) {
    Route rt;
    rt.e0 = e0; rt.e1 = e1;
    rt.c0 = w0 * ldf(alphas, e0, nAl) / (float)r;
    rt.c1 = w1 * ldf(alphas, e1, nAl) / (float)r;
    g_route[t] = rt;
  }
}

// ---------------- Main MFMA GEMM (m97 async staging): [W^T | A^T] ----------------
#define BM 128
#define BN 128
#define BK 32

__global__ __launch_bounds__(256) void gemm_main(
    const float* __restrict__ bias, long long nBias,
    float* __restrict__ Out, long long nOut,
    int K, int d_out, int Er, int T) {
  __shared__ __align__(16) u16 As[BM * BK];
  __shared__ __align__(16) u16 Bs[BN * BK];
  const int tid = threadIdx.x;
  const int w = tid >> 6, lane = tid & 63;
  const int Mb = blockIdx.y * BM;
  const int Nb = blockIdx.x * BN;
  const int wm = w >> 1, wn = w & 1;
  // staging: wave w stages 1KB chunks {2w,2w+1}; lane -> (row=lane>>2, 16B k-chunk=lane&3)
  const int chunk0 = w * 2;
  const int srow = lane >> 2;
  const int kb = (lane & 3) * 8;

  floatx4 acc[4][4];
#pragma unroll
  for (int mt = 0; mt < 4; ++mt)
#pragma unroll
    for (int nt = 0; nt < 4; ++nt) acc[mt][nt] = (floatx4){0.f, 0.f, 0.f, 0.f};

  for (int k0 = 0; k0 < K; k0 += BK) {
#pragma unroll
    for (int c = 0; c < 2; ++c) {
      const int row = (chunk0 + c) * 16 + srow;
      async_cp16(g_xb + (size_t)(Mb + row) * K + (k0 + kb), (char*)As + (chunk0 + c) * 1024);
    }
#pragma unroll
    for (int c = 0; c < 2; ++c) {
      const int row = (chunk0 + c) * 16 + srow;
      const int col = Nb + row;
      const u16* g = (col >= d_out) ? g_ab + (size_t)(col - d_out) * K + (k0 + kb)
                                    : g_wb + (size_t)col * K + (k0 + kb);
      async_cp16(g, (char*)Bs + (chunk0 + c) * 1024);
    }
    __syncthreads();
    short8 a[4], b[4];
#pragma unroll
    for (int mt = 0; mt < 4; ++mt)
      a[mt] = *(const short8*)&As[(wm * 64 + mt * 16 + (lane & 15)) * BK + (lane >> 4) * 8];
#pragma unroll
    for (int nt = 0; nt < 4; ++nt)
      b[nt] = *(const short8*)&Bs[(wn * 64 + nt * 16 + (lane & 15)) * BK + (lane >> 4) * 8];
#pragma unroll
    for (int mt = 0; mt < 4; ++mt)
#pragma unroll
      for (int nt = 0; nt < 4; ++nt)
        acc[mt][nt] = __builtin_amdgcn_mfma_f32_16x16x32_bf16(a[mt], b[nt], acc[mt][nt], 0, 0, 0);
    __syncthreads();
  }

  // epilogue: C/D map col=lane&15, row=(lane>>4)*4+reg  [m89/m91-verified]
  const int colb = Nb + wn * 64 + (lane & 15);
  const int rowb = Mb + wm * 64 + (lane >> 4) * 4;
#pragma unroll
  for (int nt = 0; nt < 4; ++nt) {
    const int col = colb + nt * 16;
    const bool isOut = (col < d_out);
    const float bv = isOut ? ldf(bias, col, nBias) : 0.f;
#pragma unroll
    for (int mt = 0; mt < 4; ++mt) {
      const int row = rowb + mt * 16;
#pragma unroll
      for (int i = 0; i < 4; ++i) {
        const int rr = row + i;
        if (rr >= T) continue;
        if (isOut) {
          const long long idx = (long long)rr * d_out + col;
          if (idx < nOut) Out[idx] = acc[mt][nt][i] + bv;
        } else {
          const int mc = col - d_out;
          if (mc < Er) g_mid[(long long)rr * Er + mc] = acc[mt][nt][i];
        }
      }
    }
  }
}

// ---------------- Weighted mid: g_mw[t][j] = w_e(t)*scale_e * g_mid[t][j], bf16 ----------------
__global__ __launch_bounds__(256) void build_mw(int T, int r, int Er, int E) {
  const int t = blockIdx.x;
  if (t >= T) return;
  const Route rt = g_route[t];
  for (int j = threadIdx.x; j < Er; j += 256) {
    const int e = (r == 16) ? (j >> 4) : (j / r);
    float wgt = 0.f;
    if (e == rt.e0) wgt = rt.c0;
    else if (e == rt.e1) wgt = rt.c1;
    g_mw[(long long)t * Er + j] = f2b(wgt * g_mid[(long long)t * Er + j]);
  }
}

// ---------------- GEMM2: Out += M'[T x Er] @ W2[d_out x Er]^T (K = Er = 256) ----------------
__global__ __launch_bounds__(256) void gemm_lora(
    float* __restrict__ Out, long long nOut, int Kc, int d_out, int T) {
  __shared__ __align__(16) u16 As[BM * BK];
  __shared__ __align__(16) u16 Bs[BN * BK];
  const int tid = threadIdx.x;
  const int w = tid >> 6, lane = tid & 63;
  const int Mb = blockIdx.y * BM;
  const int Nb = blockIdx.x * BN;
  const int wm = w >> 1, wn = w & 1;
  const int chunk0 = w * 2;
  const int srow = lane >> 2;
  const int kb = (lane & 3) * 8;

  floatx4 acc[4][4];
#pragma unroll
  for (int mt = 0; mt < 4; ++mt)
#pragma unroll
    for (int nt = 0; nt < 4; ++nt) acc[mt][nt] = (floatx4){0.f, 0.f, 0.f, 0.f};

  for (int k0 = 0; k0 < Kc; k0 += BK) {
#pragma unroll
    for (int c = 0; c < 2; ++c) {
      const int row = (chunk0 + c) * 16 + srow;
      async_cp16(g_mw + (size_t)(Mb + row) * Kc + (k0 + kb), (char*)As + (chunk0 + c) * 1024);
      async_cp16(g_w2 + (size_t)(Nb + row) * Kc + (k0 + kb), (char*)Bs + (chunk0 + c) * 1024);
    }
    __syncthreads();
    short8 a[4], b[4];
#pragma unroll
    for (int mt = 0; mt < 4; ++mt)
      a[mt] = *(const short8*)&As[(wm * 64 + mt * 16 + (lane & 15)) * BK + (lane >> 4) * 8];
#pragma unroll
    for (int nt = 0; nt < 4; ++nt)
      b[nt] = *(const short8*)&Bs[(wn * 64 + nt * 16 + (lane & 15)) * BK + (lane >> 4) * 8];
#pragma unroll
    for (int mt = 0; mt < 4; ++mt)
#pragma unroll
      for (int nt = 0; nt < 4; ++nt)
        acc[mt][nt] = __builtin_amdgcn_mfma_f32_16x16x32_bf16(a[mt], b[nt], acc[mt][nt], 0, 0, 0);
    __syncthreads();
  }

  const int colb = Nb + wn * 64 + (lane & 15);
  const int rowb = Mb + wm * 64 + (lane >> 4) * 4;
#pragma unroll
  for (int nt = 0; nt < 4; ++nt) {
    const int col = colb + nt * 16;
#pragma unroll
    for (int mt = 0; mt < 4; ++mt) {
      const int row = rowb + mt * 16;
#pragma unroll
      for (int i = 0; i < 4; ++i) {
        const int rr = row + i;
        if (rr >= T) continue;
        const long long idx = (long long)rr * d_out + col;
        if (idx < nOut) Out[idx] += acc[mt][nt][i];
      }
    }
  }
}

extern "C" void kernel_launch(void* const* d_in, const int* in_sizes, int n_in,
                              void* d_out, int out_size, void* d_ws, size_t ws_size,
                              hipStream_t stream) {
  if (n_in < 7 || !d_out) return;
  const float* x    = (const float*)d_in[0];
  const float* W    = (const float*)d_in[1];
  const float* bias = (const float*)d_in[2];
  const float* A    = (const float*)d_in[3];
  const float* B    = (const float*)d_in[4];
  const float* gv   = (const float*)d_in[5];
  const float* al   = (const float*)d_in[6];
  const int has_topk = (n_in > 7 && in_sizes[7] >= 1) ? 1 : 0;
  const int* topk = has_topk ? (const int*)d_in[7] : nullptr;
  float* out = (float*)d_out;

  const long long nX = in_sizes[0], nW = in_sizes[1], nBias = in_sizes[2];
  const long long nA = in_sizes[3], nB = in_sizes[4], nG = in_sizes[5], nAl = in_sizes[6];
  const long long nOut = (long long)out_size;

  const int E = in_sizes[6] > 0 ? in_sizes[6] : 1;               // 16
  int d = (int)(nG / E); if (d < 1) d = 1;                       // 2048
  const int d_out_dim = in_sizes[2] > 0 ? in_sizes[2] : 1;       // 2048
  int T = (int)(nX / d);                                         // 8192
  int r = (int)(nA / ((long long)E * d)); if (r < 1) r = 1;      // 16
  const int Er = E * r;                                          // 256
  if (T < 1) return;
  if (T > MAX_T) T = MAX_T;
  if (d > MAX_K || d_out_dim > MAX_DOUT || Er > MAX_ER) return;  // static capacity guard

  // independent prep
  cvt_bf16<<<4096, 256, 0, stream>>>(W, nW, 1);
  cvt_bf16<<<512, 256, 0, stream>>>(A, nA, 2);
  build_w2<<<(d_out_dim * E + 255) / 256, 256, 0, stream>>>(B, nB, d_out_dim, r, E, Er);
  router_cvtx<<<(T + 3) / 4, 256, 0, stream>>>(x, nX, gv, nG, al, nAl, topk, has_topk, T, d, r, E);

  // main GEMM: C[T x (d_out+Er)]
  dim3 grid1((d_out_dim + Er + BN - 1) / BN, (T + BM - 1) / BM);
  gemm_main<<<grid1, 256, 0, stream>>>(bias, nBias, out, nOut, d, d_out_dim, Er, T);

  // LoRA combine as GEMM
  build_mw<<<T, 256, 0, stream>>>(T, r, Er, E);
  dim3 grid2((d_out_dim + BN - 1) / BN, (T + BM - 1) / BM);
  gemm_lora<<<grid2, 256, 0, stream>>>(out, nOut, Er, d_out_dim, T);
}